// Round 10
// baseline (245.188 us; speedup 1.0000x reference)
//
#include <hip/hip_runtime.h>
#include <hip/hip_cooperative_groups.h>

namespace cg = cooperative_groups;

// Problem constants (reference: H=W=64, C=2048, IMG=224)
#define HW    4096          // H*W rows
#define CDIM  2048          // channels (K)
#define IMG   224
#define NTKI  64            // K tiles of 32 (i8): CDIM/32
#define LROW  528           // LDS i8 row stride bytes (512 + 16 pad)
#define QSCALE 21.166666f   // 127/6: 6-sigma clip
#define NS    32            // GEMM K stages: 2048 / 64

typedef int   int4v  __attribute__((ext_vector_type(4)));    // 16 i8, 4 VGPRs
typedef int   i32x16 __attribute__((ext_vector_type(16)));
typedef char  char4v __attribute__((ext_vector_type(4)));

__device__ __forceinline__ i32x16 zi16() {
    i32x16 z;
#pragma unroll
    for (int i = 0; i < 16; ++i) z[i] = 0;
    return z;
}
__device__ __forceinline__ char quant8(float x) {
    int r = __float2int_rn(x * QSCALE);
    r = min(max(r, -127), 127);
    return (char)r;
}
__device__ __forceinline__ void gload_lds16(const char* g, char* l) {
    __builtin_amdgcn_global_load_lds(
        (const __attribute__((address_space(1))) void*)g,
        (__attribute__((address_space(3))) void*)l, 16, 0, 0);
}

// ---------------------------------------------------------------------------
// ONE cooperative kernel, 256 blocks x 512 threads (1 block/CU, 128KB LDS):
//   Phase A: fp32 -> i8 fragment-pack + partial colsums P   (proven convert)
//   Phase B: i8 GEMM-max, R2 structure (best measured, ~40us): 256^2 tile,
//            8 waves 2Mx4N, 4-deep LDS, 2-phase/stage, counted vmcnt, duty
//            blocks finalize P -> s
//   Phase C: exact-fp32 saliency matvecs (accuracy-critical)
//   Phase D: global max + normalize + bilinear 64->224
// grid.sync() between phases replaces 3 dispatch boundaries (R8 evidence:
// per-dispatch overhead ~5-10us each) and provides the device-scope fences
// required across XCDs (guide G16: cooperative launch is the sanctioned
// grid-wide barrier).
__global__ __launch_bounds__(512, 2) void simcam_fused(
    const float* __restrict__ feat,
    char* __restrict__ Ap, char* __restrict__ Bp,
    float* __restrict__ P, float* __restrict__ s,
    float* __restrict__ blockmax, float* __restrict__ sal,
    float* __restrict__ out) {
    __shared__ char smem[131072];
    __shared__ int wred[8];
    __shared__ float wmax8[8];
    __shared__ float rM;
    cg::grid_group grid = cg::this_grid();

    const int tid  = threadIdx.x;
    const int bid  = blockIdx.x;          // 0..255
    const int lane = tid & 63;
    const int wave = tid >> 6;            // 0..7

    // ================= Phase A: convert + pack + partial colsums ==========
    {
        const int h = tid >> 8;           // half 0/1 (each half = one old block)
        const int t = tid & 255;
        const int u = bid * 2 + h;        // old-unit 0..511
        const int kb  = u >> 7;           // 0..3   k-block of 512
        const int rm  = (u >> 1) & 63;    // 0..63  64-row group
        const int mat = u & 1;
        char*  tile = smem + h * 33792;                   // 64*528
        float* csum = (float*)(smem + 67584) + (h << 9);  // 512 floats/half
        const int kb0 = kb * 512;
        const float* src = feat + (size_t)mat * HW * CDIM
                         + (size_t)(rm * 64) * CDIM + kb0;

        const int cc = (t & 127) * 4;
        float a0 = 0.f, a1 = 0.f, a2 = 0.f, a3 = 0.f;
#pragma unroll
        for (int j = 0; j < 32; ++j) {
            const int r = j * 2 + (t >> 7);
            float4 v = *(const float4*)&src[(size_t)r * CDIM + cc];
            a0 += v.x; a1 += v.y; a2 += v.z; a3 += v.w;
            char4v q;
            q[0] = quant8(v.x); q[1] = quant8(v.y);
            q[2] = quant8(v.z); q[3] = quant8(v.w);
            *(char4v*)&tile[r * LROW + cc] = q;
        }
        if (t >= 128) {
            csum[cc + 0] = a0; csum[cc + 1] = a1;
            csum[cc + 2] = a2; csum[cc + 3] = a3;
        }
        __syncthreads();
        if (t < 128) {
            float4 p;
            p.x = a0 + csum[cc + 0]; p.y = a1 + csum[cc + 1];
            p.z = a2 + csum[cc + 2]; p.w = a3 + csum[cc + 3];
            *(float4*)&P[((size_t)mat * 64 + rm) * CDIM + kb0 + cc] = p;
        }
        // pack: 2 tm-tiles x 16 tk-tiles per half; conflict-free ds_read_b128
        const int l = t & 63, w = t >> 6;         // w 0..3 within half
        char* dstbase = mat ? Bp : Ap;
#pragma unroll
        for (int i = 0; i < 8; ++i) {
            const int t2  = w * 8 + i;            // local tile 0..31
            const int tml = t2 >> 4, tkl = t2 & 15;
            int4v v = *(const int4v*)
                &tile[(tml * 32 + (l & 31)) * LROW + tkl * 32 + (l >> 5) * 16];
            const int tm  = rm * 2 + tml;
            const int tkg = kb * 16 + tkl;
            *(int4v*)&dstbase[((size_t)(tm * NTKI + tkg) * 64 + l) * 16] = v;
        }
    }

    grid.sync();

    // ================= Phase B: i8 GEMM-max (R2 structure, verbatim) ======
    {
        char* lds = smem;                          // 4 x 32KB stage buffers
        const int wm = wave >> 2, wn = wave & 3;   // 2 x 4 wave grid
        const int bm = bid >> 4, bn = bid & 15;

        const char* gb[4];
        int loff[4];
#pragma unroll
        for (int q = 0; q < 4; ++q) {
            const int c = wave * 4 + q;
            const int kk = c & 1;
            if (c < 16) {
                const int il = c >> 1;
                gb[q] = Ap + ((size_t)(bm * 8 + il) * NTKI + kk) * 1024 + lane * 16;
                loff[q] = (il * 2 + kk) * 1024;
            } else {
                const int jl = (c - 16) >> 1;
                gb[q] = Bp + ((size_t)(bn * 8 + jl) * NTKI + kk) * 1024 + lane * 16;
                loff[q] = 16384 + (jl * 2 + kk) * 1024;
            }
        }

#define ISSUE_STAGE(S) do {                                         \
        char* buf_ = lds + (((S) & 3) << 15);                       \
        _Pragma("unroll")                                           \
        for (int q = 0; q < 4; ++q)                                 \
            gload_lds16(gb[q] + (size_t)(S) * 2048, buf_ + loff[q]);\
    } while (0)
#define ISSUE_HALF(S, Q0) do {                                      \
        char* buf_ = lds + (((S) & 3) << 15);                       \
        gload_lds16(gb[Q0]     + (size_t)(S) * 2048, buf_ + loff[Q0]);     \
        gload_lds16(gb[Q0 + 1] + (size_t)(S) * 2048, buf_ + loff[Q0 + 1]); \
    } while (0)

        ISSUE_STAGE(0); ISSUE_STAGE(1); ISSUE_STAGE(2);

        // colsum finalize duty (16 blocks), overlapped with prologue flight
        if (bid < 16 && tid < 256) {
            const int gc = bid * 256 + tid;            // 0..4095 = mat*2048+c
            const float* Pp = P + (size_t)(gc >> 11) * 64 * CDIM + (gc & 2047);
            float sum = 0.f;
#pragma unroll 8
            for (int r = 0; r < 64; ++r) sum += Pp[(size_t)r * CDIM];
            s[gc] = sum;
        }

        asm volatile("s_waitcnt vmcnt(8)" ::: "memory");
        asm volatile("s_barrier" ::: "memory");

        const int abase = wm * 8192 + lane * 16;
        const int bbase = 16384 + wn * 4096 + lane * 16;

        i32x16 acc00 = zi16(), acc01 = zi16();
        i32x16 acc10 = zi16(), acc11 = zi16();
        i32x16 acc20 = zi16(), acc21 = zi16();
        i32x16 acc30 = zi16(), acc31 = zi16();

#define MM(i, j, A, B) acc##i##j = __builtin_amdgcn_mfma_i32_32x32x32_i8(A, B, acc##i##j, 0, 0, 0)

        for (int st = 0; st < NS; ++st) {
            const char* ab = lds + ((st & 3) << 15) + abase;
            const char* bb = lds + ((st & 3) << 15) + bbase;

            { // phase kk=0
                int4v a0 = *(const int4v*)(ab);
                int4v a1 = *(const int4v*)(ab + 2048);
                int4v a2 = *(const int4v*)(ab + 4096);
                int4v a3 = *(const int4v*)(ab + 6144);
                int4v b0 = *(const int4v*)(bb);
                int4v b1 = *(const int4v*)(bb + 2048);
                if (st + 3 < NS) ISSUE_HALF(st + 3, 0);
                asm volatile("s_barrier" ::: "memory");
                asm volatile("s_waitcnt lgkmcnt(0)" ::: "memory");
                __builtin_amdgcn_s_setprio(1);
                MM(0,0,a0,b0); MM(0,1,a0,b1);
                MM(1,0,a1,b0); MM(1,1,a1,b1);
                MM(2,0,a2,b0); MM(2,1,a2,b1);
                MM(3,0,a3,b0); MM(3,1,a3,b1);
                __builtin_amdgcn_s_setprio(0);
                asm volatile("s_barrier" ::: "memory");
            }
            { // phase kk=1
                int4v a0 = *(const int4v*)(ab + 1024);
                int4v a1 = *(const int4v*)(ab + 2048 + 1024);
                int4v a2 = *(const int4v*)(ab + 4096 + 1024);
                int4v a3 = *(const int4v*)(ab + 6144 + 1024);
                int4v b0 = *(const int4v*)(bb + 1024);
                int4v b1 = *(const int4v*)(bb + 2048 + 1024);
                if (st + 3 < NS) ISSUE_HALF(st + 3, 2);
                if (st < NS - 3)       { asm volatile("s_waitcnt vmcnt(8)" ::: "memory"); }
                else if (st == NS - 3) { asm volatile("s_waitcnt vmcnt(4)" ::: "memory"); }
                else if (st == NS - 2) { asm volatile("s_waitcnt vmcnt(0)" ::: "memory"); }
                asm volatile("s_barrier" ::: "memory");
                asm volatile("s_waitcnt lgkmcnt(0)" ::: "memory");
                __builtin_amdgcn_s_setprio(1);
                MM(0,0,a0,b0); MM(0,1,a0,b1);
                MM(1,0,a1,b0); MM(1,1,a1,b1);
                MM(2,0,a2,b0); MM(2,1,a2,b1);
                MM(3,0,a3,b0); MM(3,1,a3,b1);
                __builtin_amdgcn_s_setprio(0);
                asm volatile("s_barrier" ::: "memory");
            }
        }
#undef ISSUE_STAGE
#undef ISSUE_HALF
#undef MM

        int m = INT_MIN;
#pragma unroll
        for (int i = 0; i < 16; ++i) {
            m = max(m, acc00[i]); m = max(m, acc01[i]);
            m = max(m, acc10[i]); m = max(m, acc11[i]);
            m = max(m, acc20[i]); m = max(m, acc21[i]);
            m = max(m, acc30[i]); m = max(m, acc31[i]);
        }
#pragma unroll
        for (int off = 32; off; off >>= 1)
            m = max(m, __shfl_down(m, off));
        if (lane == 0) wred[wave] = m;
        __syncthreads();
        if (tid == 0) {
            int im = wred[0];
#pragma unroll
            for (int w2 = 1; w2 < 8; ++w2) im = max(im, wred[w2]);
            blockmax[bid] = (float)im * (1.0f / (QSCALE * QSCALE));
        }
    }

    grid.sync();

    // ================= Phase C: exact-fp32 saliency matvecs ===============
    {
#pragma unroll
        for (int rr = 0; rr < 4; ++rr) {
            const int g = bid * 32 + wave * 4 + rr;    // 0..8191
            const float* x;
            const float* sv;
            if (g < HW) { x = feat + (size_t)g * CDIM;                            sv = s + CDIM; }
            else        { x = feat + (size_t)HW * CDIM + (size_t)(g - HW) * CDIM; sv = s; }
            float a = 0.f;
#pragma unroll
            for (int it2 = 0; it2 < 8; ++it2) {
                const int c0 = it2 * 256 + lane * 4;
                float4 v  = *(const float4*)&x[c0];
                float4 w2 = *(const float4*)&sv[c0];
                a += v.x * w2.x + v.y * w2.y + v.z * w2.z + v.w * w2.w;
            }
#pragma unroll
            for (int off = 32; off; off >>= 1) a += __shfl_down(a, off);
            if (lane == 0) sal[g] = a;
        }
    }

    grid.sync();

    // ================= Phase D: normalize + bilinear 64 -> 224 ============
    {
        float m = -3.4e38f;
        if (tid < 256) m = blockmax[tid];
#pragma unroll
        for (int off = 32; off; off >>= 1) m = fmaxf(m, __shfl_down(m, off));
        if (lane == 0) wmax8[wave] = m;
        __syncthreads();
        if (tid == 0) {
            float mm = wmax8[0];
#pragma unroll
            for (int w2 = 1; w2 < 8; ++w2) mm = fmaxf(mm, wmax8[w2]);
            rM = 1.0f / mm;
        }
        __syncthreads();

        const int idx = bid * 512 + tid;               // 131072 >= 100352
        if (idx < 2 * IMG * IMG) {
            const int ch  = idx / (IMG * IMG);
            const int rem = idx % (IMG * IMG);
            const int oy = rem / IMG, ox = rem % IMG;
            const float scale = 64.0f / (float)IMG;
            const float sy = ((float)oy + 0.5f) * scale - 0.5f;
            const float sx = ((float)ox + 0.5f) * scale - 0.5f;
            const float fy0 = floorf(sy), fx0 = floorf(sx);
            const float wy = sy - fy0, wx = sx - fx0;
            int y0 = (int)fy0, x0 = (int)fx0;
            int y1 = min(max(y0 + 1, 0), 63), x1 = min(max(x0 + 1, 0), 63);
            y0 = min(max(y0, 0), 63); x0 = min(max(x0, 0), 63);
            const float* p = sal + ch * HW;
            const float v00 = p[y0 * 64 + x0], v01 = p[y0 * 64 + x1];
            const float v10 = p[y1 * 64 + x0], v11 = p[y1 * 64 + x1];
            out[idx] = ((1.f - wy) * ((1.f - wx) * v00 + wx * v01) +
                        wy * ((1.f - wx) * v10 + wx * v11)) * rM;
        }
    }
}

// ---------------------------------------------------------------------------
extern "C" void kernel_launch(void* const* d_in, const int* in_sizes, int n_in,
                              void* d_out, int out_size, void* d_ws, size_t ws_size,
                              hipStream_t stream) {
    const float* feat = (const float*)d_in[0];   // [2,64,64,2048] fp32
    float* out = (float*)d_out;                  // [2,224,224] fp32

    // workspace layout
    char* ws = (char*)d_ws;
    char* Ap = ws;                                                  // 8 MB packed i8
    char* Bp = ws + (size_t)8 * 1024 * 1024;                        // 8 MB packed i8
    float* P    = (float*)(ws + (size_t)16 * 1024 * 1024);          // 2*64*2048 = 1 MB
    float* s    = P + 2 * 64 * CDIM;                                // 2*2048
    float* bmax = s + 2 * CDIM;                                     // 256 used
    float* sal  = bmax + 1024;                                      // 8192

    void* kargs[] = { (void*)&feat, (void*)&Ap, (void*)&Bp, (void*)&P,
                      (void*)&s, (void*)&bmax, (void*)&sal, (void*)&out };
    hipLaunchCooperativeKernel((const void*)simcam_fused,
                               dim3(256), dim3(512), kargs, 0, stream);
}